// Round 10
// baseline (153.607 us; speedup 1.0000x reference)
//
#include <hip/hip_runtime.h>

#define NN 8192      // nodes
#define FI 512       // in features
#define FH 512       // hidden features

typedef __attribute__((ext_vector_type(8))) short short8;
typedef __attribute__((ext_vector_type(4))) float f32x4;

__device__ __forceinline__ unsigned short f2bf(float f) {
    unsigned u = __float_as_uint(f);
    unsigned r = (u + 0x7fff + ((u >> 16) & 1)) >> 16;   // RNE
    return (unsigned short)r;
}

#define GLOAD_LDS16(g, l)                                                        \
    __builtin_amdgcn_global_load_lds((__attribute__((address_space(1))) const void*)(g), \
                                     (__attribute__((address_space(3))) void*)(l), 16, 0, 0)

// =============== K1: prep =================================================
//  blocks 0..1023    : cvt x -> bf16 (4 float4/thread)
//  blocks 1024..1087 : W1 transpose -> bf16 via padded LDS tile
//  blocks 1088..1215 : zero deg_in/deg_out/cursor/cursorT (contiguous 128 KB)
//  blocks 1216..1247 : ohe = o@Wl + bl ; h2 = b2
__global__ __launch_bounds__(256) void k_prep(const float* __restrict__ x,
                                              const float* __restrict__ W1,
                                              const float* __restrict__ o,
                                              const float* __restrict__ Wl,
                                              const float* __restrict__ bl,
                                              const float* __restrict__ b2,
                                              unsigned short* __restrict__ xb,
                                              unsigned short* __restrict__ W1t,
                                              int* __restrict__ zero_base,
                                              float* __restrict__ ohe,
                                              float* __restrict__ h2) {
    int b = blockIdx.x, t = threadIdx.x;
    if (b < 1024) {
        #pragma unroll
        for (int u = 0; u < 4; ++u) {
            int i = (b * 4 + u) * 256 + t;           // 1M float4 units total
            float4 v = reinterpret_cast<const float4*>(x)[i];
            ushort4 h;
            h.x = f2bf(v.x); h.y = f2bf(v.y); h.z = f2bf(v.z); h.w = f2bf(v.w);
            reinterpret_cast<ushort4*>(xb)[i] = h;
        }
    } else if (b < 1088) {
        __shared__ float tile[64][65];
        int bi = (b - 1024) >> 3;                    // k-tile
        int bj = (b - 1024) & 7;                     // n-tile
        int c = t & 63, r0 = t >> 6;
        #pragma unroll
        for (int rr = 0; rr < 16; ++rr) {
            int row = rr * 4 + r0;
            tile[row][c] = W1[(size_t)(bi * 64 + row) * FH + bj * 64 + c];
        }
        __syncthreads();
        #pragma unroll
        for (int rr = 0; rr < 16; ++rr) {
            int row = rr * 4 + r0;                   // n within tile
            W1t[(size_t)(bj * 64 + row) * FI + bi * 64 + c] = f2bf(tile[c][row]);
        }
    } else if (b < 1216) {
        zero_base[(b - 1088) * 256 + t] = 0;         // 32768 ints
    } else {
        int v = (b - 1216) * 256 + t;
        float4 ov = *reinterpret_cast<const float4*>(&o[(size_t)v * 4]);
        ohe[v] = ov.x * Wl[0] + ov.y * Wl[1] + ov.z * Wl[2] + ov.w * Wl[3] + bl[0];
        h2[v] = b2[0];
    }
}

// =============== K2: GEMM (blocks 0..1023) + degree count (1024..2079) ==========
__global__ __launch_bounds__(256) void k_gemmdeg(const unsigned short* __restrict__ xb,
                                                 const unsigned short* __restrict__ W1t,
                                                 unsigned char* __restrict__ h8,
                                                 const int* __restrict__ srcE,
                                                 const int* __restrict__ dstE, int E,
                                                 int* __restrict__ deg_in,
                                                 int* __restrict__ deg_out) {
    __shared__ __align__(16) unsigned short As[64 * 64];
    __shared__ __align__(16) unsigned short Bs[64 * 64];
    int bid = blockIdx.x, tid = threadIdx.x;

    if (bid >= 1024) {               // ---- degree count ----
        int i = (bid - 1024) * 256 + tid;
        if (i < E) {
            atomicAdd(&deg_in[dstE[i]], 1);
            atomicAdd(&deg_out[srcE[i]], 1);
        }
        return;
    }

    // ---- bf16 MFMA GEMM, BM=BN=BK=64; epilogue -> fp8 e4m3 ----
    int lane = tid & 63;
    int wave = tid >> 6;
    int wm = wave >> 1, wn = wave & 1;
    int bm = (bid >> 3) * 64, bn = (bid & 7) * 64;

    f32x4 acc[2][2] = {};
    int r  = lane & 15;
    int s0 = lane >> 4;

    for (int kt = 0; kt < FI / 64; ++kt) {
        #pragma unroll
        for (int t = 0; t < 2; ++t) {
            int q   = t * 256 + tid;
            int row = q >> 3;
            int sl  = q & 7;
            int sg  = sl ^ (row & 7);
            GLOAD_LDS16(xb  + (size_t)(bm + row) * FI + kt * 64 + sg * 8, As + q * 8);
            GLOAD_LDS16(W1t + (size_t)(bn + row) * FI + kt * 64 + sg * 8, Bs + q * 8);
        }
        __syncthreads();
        #pragma unroll
        for (int kc = 0; kc < 2; ++kc) {
            short8 a[2], b[2];
            #pragma unroll
            for (int m = 0; m < 2; ++m) {
                int row = wm * 32 + m * 16 + r;
                int sl  = (kc * 4 + s0) ^ (row & 7);
                a[m] = *reinterpret_cast<const short8*>(As + row * 64 + sl * 8);
            }
            #pragma unroll
            for (int n = 0; n < 2; ++n) {
                int row = wn * 32 + n * 16 + r;
                int sl  = (kc * 4 + s0) ^ (row & 7);
                b[n] = *reinterpret_cast<const short8*>(Bs + row * 64 + sl * 8);
            }
            #pragma unroll
            for (int m = 0; m < 2; ++m)
                #pragma unroll
                for (int n = 0; n < 2; ++n)
                    acc[m][n] = __builtin_amdgcn_mfma_f32_16x16x32_bf16(a[m], b[n], acc[m][n], 0, 0, 0);
        }
        __syncthreads();
    }
    #pragma unroll
    for (int m = 0; m < 2; ++m)
        #pragma unroll
        for (int n = 0; n < 2; ++n) {
            int col = bn + wn * 32 + n * 16 + (lane & 15);
            int rw0 = bm + wm * 32 + m * 16 + (lane >> 4) * 4;
            #pragma unroll
            for (int reg = 0; reg < 4; ++reg) {
                float v = acc[m][n][reg];
                int pk = __builtin_amdgcn_cvt_pk_fp8_f32(v, v, 0, false);
                h8[(size_t)(rw0 + reg) * FH + col] = (unsigned char)(pk & 0xff);
            }
        }
}

// ========== K3: single-block dual prefix scan (deg_in -> row_ptr + dinv;
//                deg_out -> row_ptrT) ==========
__global__ __launch_bounds__(1024) void k_scan(const int* __restrict__ deg_in,
                                               const int* __restrict__ deg_out,
                                               int* __restrict__ row_ptr,
                                               int* __restrict__ row_ptrT,
                                               float* __restrict__ dinv) {
    __shared__ int lds[1024];
    int tid = threadIdx.x;
    int base = tid * 8;

    // pass 1: deg_in
    {
        int l[8]; int s = 0;
        #pragma unroll
        for (int u = 0; u < 8; ++u) {
            l[u] = deg_in[base + u] + 1;                 // +1 self loop
            dinv[base + u] = rsqrtf((float)l[u]);
            s += l[u];
        }
        lds[tid] = s;
        __syncthreads();
        for (int off = 1; off < 1024; off <<= 1) {
            int add = (tid >= off) ? lds[tid - off] : 0;
            __syncthreads();
            lds[tid] += add;
            __syncthreads();
        }
        int run = lds[tid] - s;
        #pragma unroll
        for (int u = 0; u < 8; ++u) { row_ptr[base + u] = run; run += l[u]; }
        if (tid == 1023) row_ptr[NN] = lds[1023];
    }
    __syncthreads();
    // pass 2: deg_out
    {
        int l[8]; int s = 0;
        #pragma unroll
        for (int u = 0; u < 8; ++u) { l[u] = deg_out[base + u] + 1; s += l[u]; }
        lds[tid] = s;
        __syncthreads();
        for (int off = 1; off < 1024; off <<= 1) {
            int add = (tid >= off) ? lds[tid - off] : 0;
            __syncthreads();
            lds[tid] += add;
            __syncthreads();
        }
        int run = lds[tid] - s;
        #pragma unroll
        for (int u = 0; u < 8; ++u) { row_ptrT[base + u] = run; run += l[u]; }
        if (tid == 1023) row_ptrT[NN] = lds[1023];
    }
}

// =============== K4: CSR + CSR^T fill (global row_ptr) ==========================
__global__ void k_fill(const int* __restrict__ srcE, const int* __restrict__ dstE, int E,
                       const float* __restrict__ dinv,
                       const int* __restrict__ row_ptr, const int* __restrict__ row_ptrT,
                       int* __restrict__ cursor, int* __restrict__ cursorT,
                       int2* __restrict__ csr, int2* __restrict__ csrT) {
    int i = blockIdx.x * blockDim.x + threadIdx.x;
    if (i < E) {
        int s = srcE[i], d = dstE[i];
        int wb = __float_as_int(dinv[s] * dinv[d]);
        int p  = row_ptr[d]  + atomicAdd(&cursor[d], 1);
        csr[p]  = make_int2(s, wb);
        int pT = row_ptrT[s] + atomicAdd(&cursorT[s], 1);
        csrT[pT] = make_int2(d, wb);
    } else if (i < E + NN) {
        int v = i - E;
        float dv = dinv[v];
        int wb = __float_as_int(dv * dv);
        int p  = row_ptr[v]  + atomicAdd(&cursor[v], 1);
        csr[p]  = make_int2(v, wb);
        int pT = row_ptrT[v] + atomicAdd(&cursorT[v], 1);
        csrT[pT] = make_int2(v, wb);
    }
}

// ---- fp8x8 accumulate helper ----
__device__ __forceinline__ void acc8(float* __restrict__ acc, uint2 rv, float w) {
    acc[0] += w * __builtin_amdgcn_cvt_f32_fp8((int)rv.x, 0);
    acc[1] += w * __builtin_amdgcn_cvt_f32_fp8((int)rv.x, 1);
    acc[2] += w * __builtin_amdgcn_cvt_f32_fp8((int)rv.x, 2);
    acc[3] += w * __builtin_amdgcn_cvt_f32_fp8((int)rv.x, 3);
    acc[4] += w * __builtin_amdgcn_cvt_f32_fp8((int)rv.y, 0);
    acc[5] += w * __builtin_amdgcn_cvt_f32_fp8((int)rv.y, 1);
    acc[6] += w * __builtin_amdgcn_cvt_f32_fp8((int)rv.y, 2);
    acc[7] += w * __builtin_amdgcn_cvt_f32_fp8((int)rv.y, 3);
}

// =============== K5: z[v] in-register, then scatter w*z into h2 =================
__global__ __launch_bounds__(256) void k_agg(const unsigned char* __restrict__ h8,
                                             const int* __restrict__ row_ptr,
                                             const int* __restrict__ row_ptrT,
                                             const int2* __restrict__ csr,
                                             const int2* __restrict__ csrT,
                                             const float* __restrict__ b1,
                                             const float* __restrict__ W2,
                                             float* __restrict__ h2) {
    int lane = threadIdx.x & 63;
    int v = blockIdx.x * 4 + (threadIdx.x >> 6);
    float acc[8] = {};
    int p0 = row_ptr[v], p1 = row_ptr[v + 1];
    for (int base = p0; base < p1; base += 64) {
        int cnt = p1 - base; if (cnt > 64) cnt = 64;
        int2 sw = (lane < cnt) ? csr[base + lane] : make_int2(0, 0);
        int j = 0;
        for (; j + 4 <= cnt; j += 4) {
            int   s0 = __shfl(sw.x, j),     s1 = __shfl(sw.x, j + 1);
            int   s2 = __shfl(sw.x, j + 2), s3 = __shfl(sw.x, j + 3);
            float w0 = __int_as_float(__shfl(sw.y, j));
            float w1 = __int_as_float(__shfl(sw.y, j + 1));
            float w2 = __int_as_float(__shfl(sw.y, j + 2));
            float w3 = __int_as_float(__shfl(sw.y, j + 3));
            uint2 r0 = *reinterpret_cast<const uint2*>(h8 + (size_t)s0 * FH + lane * 8);
            uint2 r1 = *reinterpret_cast<const uint2*>(h8 + (size_t)s1 * FH + lane * 8);
            uint2 r2 = *reinterpret_cast<const uint2*>(h8 + (size_t)s2 * FH + lane * 8);
            uint2 r3 = *reinterpret_cast<const uint2*>(h8 + (size_t)s3 * FH + lane * 8);
            acc8(acc, r0, w0);
            acc8(acc, r1, w1);
            acc8(acc, r2, w2);
            acc8(acc, r3, w3);
        }
        for (; j < cnt; ++j) {
            int   sj = __shfl(sw.x, j);
            float wj = __int_as_float(__shfl(sw.y, j));
            uint2 rj = *reinterpret_cast<const uint2*>(h8 + (size_t)sj * FH + lane * 8);
            acc8(acc, rj, wj);
        }
    }
    const float4* b4 = reinterpret_cast<const float4*>(b1 + lane * 8);
    const float4* w4 = reinterpret_cast<const float4*>(W2 + lane * 8);
    float4 b0 = b4[0], bs1 = b4[1];
    float4 w0 = w4[0], ws1 = w4[1];
    float val = fmaxf(acc[0] + b0.x, 0.f) * w0.x + fmaxf(acc[1] + b0.y, 0.f) * w0.y
              + fmaxf(acc[2] + b0.z, 0.f) * w0.z + fmaxf(acc[3] + b0.w, 0.f) * w0.w
              + fmaxf(acc[4] + bs1.x, 0.f) * ws1.x + fmaxf(acc[5] + bs1.y, 0.f) * ws1.y
              + fmaxf(acc[6] + bs1.z, 0.f) * ws1.z + fmaxf(acc[7] + bs1.w, 0.f) * ws1.w;
    #pragma unroll
    for (int off = 32; off; off >>= 1) val += __shfl_xor(val, off);
    // scatter layer-2: h2[d] += w * z[v] over v's out-edges (weights symmetric)
    int q0 = row_ptrT[v], q1 = row_ptrT[v + 1];
    for (int p = q0 + lane; p < q1; p += 64) {
        int2 sw = csrT[p];
        atomicAdd(&h2[sw.x], __int_as_float(sw.y) * val);
    }
}

// =============== K6: out[i][j] = h2[j] + ohe[i] (268 MB, nt stores) ==============
__global__ __launch_bounds__(256) void k_out(const float* __restrict__ h2,
                                             const float* __restrict__ ohe,
                                             f32x4* __restrict__ out) {
    int i0 = blockIdx.x * 4;
    int t  = threadIdx.x;
    f32x4 h[8];
    #pragma unroll
    for (int u = 0; u < 8; ++u) h[u] = reinterpret_cast<const f32x4*>(h2)[u * 256 + t];
    #pragma unroll
    for (int rr = 0; rr < 4; ++rr) {
        float oi = ohe[i0 + rr];
        f32x4* dst = out + (size_t)(i0 + rr) * 2048;
        #pragma unroll
        for (int u = 0; u < 8; ++u) {
            f32x4 w = h[u] + oi;
            __builtin_nontemporal_store(w, &dst[u * 256 + t]);
        }
    }
}

extern "C" void kernel_launch(void* const* d_in, const int* in_sizes, int n_in,
                              void* d_out, int out_size, void* d_ws, size_t ws_size,
                              hipStream_t stream) {
    const float* x  = (const float*)d_in[0];
    const float* o  = (const float*)d_in[1];
    const int*   ei = (const int*)d_in[2];
    const float* W1 = (const float*)d_in[3];
    const float* b1 = (const float*)d_in[4];
    const float* W2 = (const float*)d_in[5];
    const float* b2 = (const float*)d_in[6];
    const float* Wl = (const float*)d_in[7];
    const float* bl = (const float*)d_in[8];
    float* out = (float*)d_out;

    const int E = in_sizes[2] / 2;
    const int* src = ei;
    const int* dst = ei + E;

    // workspace carve-up (256B aligned)
    char* p = (char*)d_ws;
    auto alloc = [&](size_t bytes) {
        char* r = p;
        p += (bytes + 255) & ~(size_t)255;
        return r;
    };
    int*   deg_in   = (int*)  alloc(NN * 4);   // these four contiguous (zeroed as one span)
    int*   deg_out  = (int*)  alloc(NN * 4);
    int*   cursor   = (int*)  alloc(NN * 4);
    int*   cursorT  = (int*)  alloc(NN * 4);
    int*   row_ptr  = (int*)  alloc((NN + 1) * 4);
    int*   row_ptrT = (int*)  alloc((NN + 1) * 4);
    float* dinv     = (float*)alloc(NN * 4);
    int2*  csr      = (int2*) alloc((size_t)(E + NN) * 8);
    int2*  csrT     = (int2*) alloc((size_t)(E + NN) * 8);
    unsigned short* xb  = (unsigned short*)alloc((size_t)NN * FI * 2);
    unsigned short* W1t = (unsigned short*)alloc((size_t)FH * FI * 2);
    unsigned char*  h8  = (unsigned char*) alloc((size_t)NN * FH);
    float* h2      = (float*)alloc(NN * 4);
    float* ohe     = (float*)alloc(NN * 4);

    k_prep   <<<1248, 256, 0, stream>>>(x, W1, o, Wl, bl, b2, xb, W1t, deg_in, ohe, h2);
    k_gemmdeg<<<1024 + (E + 255) / 256, 256, 0, stream>>>(xb, W1t, h8, src, dst, E,
                                                          deg_in, deg_out);
    k_scan   <<<1, 1024, 0, stream>>>(deg_in, deg_out, row_ptr, row_ptrT, dinv);
    k_fill   <<<(E + NN + 255) / 256, 256, 0, stream>>>(src, dst, E, dinv,
                                                        row_ptr, row_ptrT,
                                                        cursor, cursorT, csr, csrT);
    k_agg    <<<NN / 4, 256, 0, stream>>>(h8, row_ptr, row_ptrT, csr, csrT, b1, W2, h2);
    k_out    <<<NN / 4, 256, 0, stream>>>(h2, ohe, (f32x4*)out);
}

// Round 11
// 141.348 us; speedup vs baseline: 1.0867x; 1.0867x over previous
//
#include <hip/hip_runtime.h>

#define NN 8192      // nodes
#define FI 512       // in features
#define FH 512       // hidden features

typedef __attribute__((ext_vector_type(8))) short short8;
typedef __attribute__((ext_vector_type(4))) float f32x4;
typedef __attribute__((ext_vector_type(2))) float f32x2;

__device__ __forceinline__ unsigned short f2bf(float f) {
    unsigned u = __float_as_uint(f);
    unsigned r = (u + 0x7fff + ((u >> 16) & 1)) >> 16;   // RNE
    return (unsigned short)r;
}

#define GLOAD_LDS16(g, l)                                                        \
    __builtin_amdgcn_global_load_lds((__attribute__((address_space(1))) const void*)(g), \
                                     (__attribute__((address_space(3))) void*)(l), 16, 0, 0)

// ------- fused prep:
//   blocks 0..1023    : cvt x -> bf16, grid-stride (4 float4 per thread)
//   blocks 1024..1087 : W1 transpose -> bf16 via padded LDS tile
//   blocks 1088..1119 : zero deg/cursor
__global__ __launch_bounds__(256) void k_prep(const float* __restrict__ x,
                                              const float* __restrict__ W1,
                                              unsigned short* __restrict__ xb,
                                              unsigned short* __restrict__ W1t,
                                              int* __restrict__ deg,
                                              int* __restrict__ cursor) {
    int b = blockIdx.x, t = threadIdx.x;
    if (b < 1024) {
        #pragma unroll
        for (int u = 0; u < 4; ++u) {
            int i = (b * 4 + u) * 256 + t;           // 1M float4 units total
            float4 v = reinterpret_cast<const float4*>(x)[i];
            ushort4 h;
            h.x = f2bf(v.x); h.y = f2bf(v.y); h.z = f2bf(v.z); h.w = f2bf(v.w);
            reinterpret_cast<ushort4*>(xb)[i] = h;
        }
    } else if (b < 1088) {
        __shared__ float tile[64][65];
        int bi = (b - 1024) >> 3;                    // k-tile
        int bj = (b - 1024) & 7;                     // n-tile
        int c = t & 63, r0 = t >> 6;
        #pragma unroll
        for (int rr = 0; rr < 16; ++rr) {
            int row = rr * 4 + r0;
            tile[row][c] = W1[(size_t)(bi * 64 + row) * FH + bj * 64 + c];
        }
        __syncthreads();
        #pragma unroll
        for (int rr = 0; rr < 16; ++rr) {
            int row = rr * 4 + r0;                   // n within tile
            W1t[(size_t)(bj * 64 + row) * FI + bi * 64 + c] = f2bf(tile[c][row]);
        }
    } else {
        int i = (b - 1088) * 256 + t;
        deg[i] = 0; cursor[i] = 0;
    }
}

// ---------------- degree count ----------------
__global__ void k_deg(const int* __restrict__ dst, int E, int* __restrict__ deg) {
    int i = blockIdx.x * blockDim.x + threadIdx.x;
    if (i < E) atomicAdd(&deg[dst[i]], 1);
}

// ---------------- prefix scan over row lengths (deg+1) + dinv ----------------
__global__ __launch_bounds__(1024) void k_scan(const int* __restrict__ deg,
                                               int* __restrict__ row_ptr,
                                               float* __restrict__ dinv) {
    __shared__ int lds[1024];
    int tid = threadIdx.x;
    int base = tid * 8;
    int l[8]; int s = 0;
    #pragma unroll
    for (int u = 0; u < 8; ++u) {
        l[u] = deg[base + u] + 1;                       // +1 self loop
        dinv[base + u] = rsqrtf((float)l[u]);
        s += l[u];
    }
    lds[tid] = s;
    __syncthreads();
    for (int off = 1; off < 1024; off <<= 1) {
        int add = (tid >= off) ? lds[tid - off] : 0;
        __syncthreads();
        lds[tid] += add;
        __syncthreads();
    }
    int run = lds[tid] - s;  // exclusive prefix
    #pragma unroll
    for (int u = 0; u < 8; ++u) { row_ptr[base + u] = run; run += l[u]; }
    if (tid == 1023) row_ptr[NN] = lds[1023];
}

// ---------------- CSR fill: packed (src, weight-bits) pairs ----------------
__global__ void k_fill(const int* __restrict__ src, const int* __restrict__ dst, int E,
                       const float* __restrict__ dinv, const int* __restrict__ row_ptr,
                       int* __restrict__ cursor, int2* __restrict__ csr) {
    int i = blockIdx.x * blockDim.x + threadIdx.x;
    if (i < E) {
        int s = src[i], d = dst[i];
        int p = row_ptr[d] + atomicAdd(&cursor[d], 1);
        csr[p] = make_int2(s, __float_as_int(dinv[s] * dinv[d]));
    } else if (i < E + NN) {
        int v = i - E;
        int p = row_ptr[v] + atomicAdd(&cursor[v], 1);
        csr[p] = make_int2(v, __float_as_int(dinv[v] * dinv[v]));
    }
}

// -------- bf16 MFMA GEMM: h1 = xb @ W1t^T; BM=BN=BK=64; epilogue -> fp8 e4m3 -----
__global__ __launch_bounds__(256) void k_gemm(const unsigned short* __restrict__ xb,
                                              const unsigned short* __restrict__ W1t,
                                              unsigned char* __restrict__ h8) {
    __shared__ __align__(16) unsigned short As[64 * 64];
    __shared__ __align__(16) unsigned short Bs[64 * 64];
    int tid  = threadIdx.x;
    int lane = tid & 63;
    int wave = tid >> 6;
    int wm = wave >> 1, wn = wave & 1;           // 2x2 wave grid, 32x32 per wave
    int bm = blockIdx.y * 64, bn = blockIdx.x * 64;

    f32x4 acc[2][2] = {};

    int r  = lane & 15;       // fragment row within 16
    int s0 = lane >> 4;       // 16B k-slot 0..3 (within a 32-k chunk)

    for (int kt = 0; kt < FI / 64; ++kt) {
        // stage 64x64 bf16 tiles: 512 16B-units each, 2 per thread
        #pragma unroll
        for (int t = 0; t < 2; ++t) {
            int q   = t * 256 + tid;
            int row = q >> 3;                     // 8 slots per row
            int sl  = q & 7;
            int sg  = sl ^ (row & 7);             // pre-swizzled source slot
            GLOAD_LDS16(xb  + (size_t)(bm + row) * FI + kt * 64 + sg * 8, As + q * 8);
            GLOAD_LDS16(W1t + (size_t)(bn + row) * FI + kt * 64 + sg * 8, Bs + q * 8);
        }
        __syncthreads();

        #pragma unroll
        for (int kc = 0; kc < 2; ++kc) {          // two k=32 chunks, ascending k order
            short8 a[2], b[2];
            #pragma unroll
            for (int m = 0; m < 2; ++m) {
                int row = wm * 32 + m * 16 + r;
                int sl  = (kc * 4 + s0) ^ (row & 7);
                a[m] = *reinterpret_cast<const short8*>(As + row * 64 + sl * 8);
            }
            #pragma unroll
            for (int n = 0; n < 2; ++n) {
                int row = wn * 32 + n * 16 + r;
                int sl  = (kc * 4 + s0) ^ (row & 7);
                b[n] = *reinterpret_cast<const short8*>(Bs + row * 64 + sl * 8);
            }
            #pragma unroll
            for (int m = 0; m < 2; ++m)
                #pragma unroll
                for (int n = 0; n < 2; ++n)
                    acc[m][n] = __builtin_amdgcn_mfma_f32_16x16x32_bf16(a[m], b[n], acc[m][n], 0, 0, 0);
        }
        __syncthreads();
    }

    // C/D layout: col = lane&15, row = (lane>>4)*4 + reg  [m89-verified]
    #pragma unroll
    for (int m = 0; m < 2; ++m) {
        #pragma unroll
        for (int n = 0; n < 2; ++n) {
            int col = bn + wn * 32 + n * 16 + (lane & 15);
            int rw0 = bm + wm * 32 + m * 16 + (lane >> 4) * 4;
            #pragma unroll
            for (int reg = 0; reg < 4; ++reg) {
                float v = acc[m][n][reg];
                int pk = __builtin_amdgcn_cvt_pk_fp8_f32(v, v, 0, false);
                h8[(size_t)(rw0 + reg) * FH + col] = (unsigned char)(pk & 0xff);
            }
        }
    }
}

// ---- fp8x8 packed accumulate: 4 cvt_pk + 4 pk_fma per row ----
__device__ __forceinline__ void accp(f32x2* __restrict__ acc, uint2 rv, float w) {
    f32x2 wv = {w, w};
    acc[0] += wv * __builtin_amdgcn_cvt_pk_f32_fp8((int)rv.x, false);
    acc[1] += wv * __builtin_amdgcn_cvt_pk_f32_fp8((int)rv.x, true);
    acc[2] += wv * __builtin_amdgcn_cvt_pk_f32_fp8((int)rv.y, false);
    acc[3] += wv * __builtin_amdgcn_cvt_pk_f32_fp8((int)rv.y, true);
}

// ------- fused: agg1[v] = relu(sum w*h8[src] + b1); z[v] = dot(agg1[v], W2) -------
// one wave per node; lane owns feats [lane*8, lane*8+8); fp8 row = 512B, L2-resident
__global__ __launch_bounds__(256) void k_agg(const unsigned char* __restrict__ h8,
                                             const int* __restrict__ row_ptr,
                                             const int2* __restrict__ csr,
                                             const float* __restrict__ b1,
                                             const float* __restrict__ W2,
                                             float* __restrict__ z) {
    int lane = threadIdx.x & 63;
    int v = blockIdx.x * 4 + (threadIdx.x >> 6);
    f32x2 acc[4] = {};
    int p0 = row_ptr[v], p1 = row_ptr[v + 1];
    for (int base = p0; base < p1; base += 64) {
        int cnt = p1 - base; if (cnt > 64) cnt = 64;
        int2 sw = (lane < cnt) ? csr[base + lane] : make_int2(0, 0);
        int j = 0;
        for (; j + 4 <= cnt; j += 4) {
            int   s0 = __shfl(sw.x, j),     s1 = __shfl(sw.x, j + 1);
            int   s2 = __shfl(sw.x, j + 2), s3 = __shfl(sw.x, j + 3);
            float w0 = __int_as_float(__shfl(sw.y, j));
            float w1 = __int_as_float(__shfl(sw.y, j + 1));
            float w2 = __int_as_float(__shfl(sw.y, j + 2));
            float w3 = __int_as_float(__shfl(sw.y, j + 3));
            uint2 r0 = *reinterpret_cast<const uint2*>(h8 + (size_t)s0 * FH + lane * 8);
            uint2 r1 = *reinterpret_cast<const uint2*>(h8 + (size_t)s1 * FH + lane * 8);
            uint2 r2 = *reinterpret_cast<const uint2*>(h8 + (size_t)s2 * FH + lane * 8);
            uint2 r3 = *reinterpret_cast<const uint2*>(h8 + (size_t)s3 * FH + lane * 8);
            accp(acc, r0, w0);
            accp(acc, r1, w1);
            accp(acc, r2, w2);
            accp(acc, r3, w3);
        }
        for (; j < cnt; ++j) {
            int   sj = __shfl(sw.x, j);
            float wj = __int_as_float(__shfl(sw.y, j));
            uint2 rj = *reinterpret_cast<const uint2*>(h8 + (size_t)sj * FH + lane * 8);
            accp(acc, rj, wj);
        }
    }
    const f32x2* b2p = reinterpret_cast<const f32x2*>(b1 + lane * 8);
    const f32x2* w2p = reinterpret_cast<const f32x2*>(W2 + lane * 8);
    float val = 0.f;
    #pragma unroll
    for (int q = 0; q < 4; ++q) {
        f32x2 t = acc[q] + b2p[q];
        t.x = fmaxf(t.x, 0.f);
        t.y = fmaxf(t.y, 0.f);
        f32x2 r = t * w2p[q];
        val += r.x + r.y;
    }
    #pragma unroll
    for (int off = 32; off; off >>= 1) val += __shfl_down(val, off);
    if (lane == 0) z[v] = val;
}

// ---------------- aggregation 2 (scalar) + ohe ----------------
__global__ void k_node(const float* __restrict__ z,
                       const int* __restrict__ row_ptr,
                       const int2* __restrict__ csr,
                       const float* __restrict__ b2,
                       const float* __restrict__ o,
                       const float* __restrict__ Wl,
                       const float* __restrict__ bl,
                       float* __restrict__ h2, float* __restrict__ ohe) {
    int v = blockIdx.x * blockDim.x + threadIdx.x;
    if (v >= NN) return;
    float acc = 0.f;
    int p1 = row_ptr[v + 1];
    for (int p = row_ptr[v]; p < p1; ++p) {
        int2 sw = csr[p];
        acc += __int_as_float(sw.y) * z[sw.x];
    }
    h2[v] = acc + b2[0];
    float4 ov = *reinterpret_cast<const float4*>(&o[(size_t)v * 4]);
    ohe[v] = ov.x * Wl[0] + ov.y * Wl[1] + ov.z * Wl[2] + ov.w * Wl[3] + bl[0];
}

// -------- out[i][j] = h2[j] + ohe[i]; 2048 blocks, 4 rows/block, h2 row in regs ----
__global__ __launch_bounds__(256) void k_out(const float* __restrict__ h2,
                                             const float* __restrict__ ohe,
                                             float4* __restrict__ out) {
    int i0 = blockIdx.x * 4;
    int t  = threadIdx.x;
    float4 h[8];
    #pragma unroll
    for (int u = 0; u < 8; ++u) h[u] = reinterpret_cast<const float4*>(h2)[u * 256 + t];
    #pragma unroll
    for (int rr = 0; rr < 4; ++rr) {
        float oi = ohe[i0 + rr];
        float4* dst = out + (size_t)(i0 + rr) * 2048;
        #pragma unroll
        for (int u = 0; u < 8; ++u) {
            float4 v = h[u];
            dst[u * 256 + t] = make_float4(v.x + oi, v.y + oi, v.z + oi, v.w + oi);
        }
    }
}

extern "C" void kernel_launch(void* const* d_in, const int* in_sizes, int n_in,
                              void* d_out, int out_size, void* d_ws, size_t ws_size,
                              hipStream_t stream) {
    const float* x  = (const float*)d_in[0];
    const float* o  = (const float*)d_in[1];
    const int*   ei = (const int*)d_in[2];
    const float* W1 = (const float*)d_in[3];
    const float* b1 = (const float*)d_in[4];
    const float* W2 = (const float*)d_in[5];
    const float* b2 = (const float*)d_in[6];
    const float* Wl = (const float*)d_in[7];
    const float* bl = (const float*)d_in[8];
    float* out = (float*)d_out;

    const int E = in_sizes[2] / 2;
    const int* src = ei;
    const int* dst = ei + E;

    // workspace carve-up (256B aligned)
    char* p = (char*)d_ws;
    auto alloc = [&](size_t bytes) {
        char* r = p;
        p += (bytes + 255) & ~(size_t)255;
        return r;
    };
    int*   deg     = (int*)  alloc(NN * 4);
    float* dinv    = (float*)alloc(NN * 4);
    int*   row_ptr = (int*)  alloc((NN + 1) * 4);
    int*   cursor  = (int*)  alloc(NN * 4);
    int2*  csr     = (int2*) alloc((size_t)(E + NN) * 8);
    unsigned short* xb  = (unsigned short*)alloc((size_t)NN * FI * 2);
    unsigned short* W1t = (unsigned short*)alloc((size_t)FH * FI * 2);
    unsigned char*  h8  = (unsigned char*) alloc((size_t)NN * FH);
    float* z       = (float*)alloc(NN * 4);
    float* h2      = (float*)alloc(NN * 4);
    float* ohe     = (float*)alloc(NN * 4);

    k_prep <<<1120, 256, 0, stream>>>(x, W1, xb, W1t, deg, cursor);
    k_deg  <<<(E + 255) / 256, 256, 0, stream>>>(dst, E, deg);
    k_scan <<<1, 1024, 0, stream>>>(deg, row_ptr, dinv);
    k_fill <<<(E + NN + 255) / 256, 256, 0, stream>>>(src, dst, E, dinv, row_ptr, cursor, csr);
    k_gemm <<<dim3(FH / 64, NN / 64), 256, 0, stream>>>(xb, W1t, h8);
    k_agg  <<<NN / 4, 256, 0, stream>>>(h8, row_ptr, csr, b1, W2, z);
    k_node <<<(NN + 255) / 256, 256, 0, stream>>>(z, row_ptr, csr, b2, o, Wl, bl, h2, ohe);
    k_out  <<<NN / 4, 256, 0, stream>>>(h2, ohe, (float4*)out);
}

// Round 12
// 140.891 us; speedup vs baseline: 1.0903x; 1.0032x over previous
//
#include <hip/hip_runtime.h>

#define NN 8192      // nodes
#define FI 512       // in features
#define FH 512       // hidden features

typedef __attribute__((ext_vector_type(8))) short short8;
typedef __attribute__((ext_vector_type(4))) float f32x4;
typedef __attribute__((ext_vector_type(2))) float f32x2;

__device__ __forceinline__ unsigned short f2bf(float f) {
    unsigned u = __float_as_uint(f);
    unsigned r = (u + 0x7fff + ((u >> 16) & 1)) >> 16;   // RNE
    return (unsigned short)r;
}

#define GLOAD_LDS16(g, l)                                                        \
    __builtin_amdgcn_global_load_lds((__attribute__((address_space(1))) const void*)(g), \
                                     (__attribute__((address_space(3))) void*)(l), 16, 0, 0)

// ------- fused prep:
//   blocks 0..1023    : cvt x -> bf16, grid-stride (4 float4 per thread)
//   blocks 1024..1087 : W1 transpose -> bf16 via padded LDS tile
//   blocks 1088..1119 : zero deg/cursor
__global__ __launch_bounds__(256) void k_prep(const float* __restrict__ x,
                                              const float* __restrict__ W1,
                                              unsigned short* __restrict__ xb,
                                              unsigned short* __restrict__ W1t,
                                              int* __restrict__ deg,
                                              int* __restrict__ cursor) {
    int b = blockIdx.x, t = threadIdx.x;
    if (b < 1024) {
        #pragma unroll
        for (int u = 0; u < 4; ++u) {
            int i = (b * 4 + u) * 256 + t;           // 1M float4 units total
            float4 v = reinterpret_cast<const float4*>(x)[i];
            ushort4 h;
            h.x = f2bf(v.x); h.y = f2bf(v.y); h.z = f2bf(v.z); h.w = f2bf(v.w);
            reinterpret_cast<ushort4*>(xb)[i] = h;
        }
    } else if (b < 1088) {
        __shared__ float tile[64][65];
        int bi = (b - 1024) >> 3;                    // k-tile
        int bj = (b - 1024) & 7;                     // n-tile
        int c = t & 63, r0 = t >> 6;
        #pragma unroll
        for (int rr = 0; rr < 16; ++rr) {
            int row = rr * 4 + r0;
            tile[row][c] = W1[(size_t)(bi * 64 + row) * FH + bj * 64 + c];
        }
        __syncthreads();
        #pragma unroll
        for (int rr = 0; rr < 16; ++rr) {
            int row = rr * 4 + r0;                   // n within tile
            W1t[(size_t)(bj * 64 + row) * FI + bi * 64 + c] = f2bf(tile[c][row]);
        }
    } else {
        int i = (b - 1088) * 256 + t;
        deg[i] = 0; cursor[i] = 0;
    }
}

// ---------------- degree count ----------------
__global__ void k_deg(const int* __restrict__ dst, int E, int* __restrict__ deg) {
    int i = blockIdx.x * blockDim.x + threadIdx.x;
    if (i < E) atomicAdd(&deg[dst[i]], 1);
}

// ---------------- prefix scan over row lengths (deg+1) + dinv ----------------
__global__ __launch_bounds__(1024) void k_scan(const int* __restrict__ deg,
                                               int* __restrict__ row_ptr,
                                               float* __restrict__ dinv) {
    __shared__ int lds[1024];
    int tid = threadIdx.x;
    int base = tid * 8;
    int l[8]; int s = 0;
    #pragma unroll
    for (int u = 0; u < 8; ++u) {
        l[u] = deg[base + u] + 1;                       // +1 self loop
        dinv[base + u] = rsqrtf((float)l[u]);
        s += l[u];
    }
    lds[tid] = s;
    __syncthreads();
    for (int off = 1; off < 1024; off <<= 1) {
        int add = (tid >= off) ? lds[tid - off] : 0;
        __syncthreads();
        lds[tid] += add;
        __syncthreads();
    }
    int run = lds[tid] - s;  // exclusive prefix
    #pragma unroll
    for (int u = 0; u < 8; ++u) { row_ptr[base + u] = run; run += l[u]; }
    if (tid == 1023) row_ptr[NN] = lds[1023];
}

// ---------------- CSR fill: packed (src, weight-bits) pairs ----------------
__global__ void k_fill(const int* __restrict__ src, const int* __restrict__ dst, int E,
                       const float* __restrict__ dinv, const int* __restrict__ row_ptr,
                       int* __restrict__ cursor, int2* __restrict__ csr) {
    int i = blockIdx.x * blockDim.x + threadIdx.x;
    if (i < E) {
        int s = src[i], d = dst[i];
        int p = row_ptr[d] + atomicAdd(&cursor[d], 1);
        csr[p] = make_int2(s, __float_as_int(dinv[s] * dinv[d]));
    } else if (i < E + NN) {
        int v = i - E;
        int p = row_ptr[v] + atomicAdd(&cursor[v], 1);
        csr[p] = make_int2(v, __float_as_int(dinv[v] * dinv[v]));
    }
}

// -------- bf16 MFMA GEMM: h1 = xb @ W1t^T; BM=BN=BK=64; epilogue -> fp8 e4m3 -----
__global__ __launch_bounds__(256) void k_gemm(const unsigned short* __restrict__ xb,
                                              const unsigned short* __restrict__ W1t,
                                              unsigned char* __restrict__ h8) {
    __shared__ __align__(16) unsigned short As[64 * 64];
    __shared__ __align__(16) unsigned short Bs[64 * 64];
    int tid  = threadIdx.x;
    int lane = tid & 63;
    int wave = tid >> 6;
    int wm = wave >> 1, wn = wave & 1;           // 2x2 wave grid, 32x32 per wave
    int bm = blockIdx.y * 64, bn = blockIdx.x * 64;

    f32x4 acc[2][2] = {};

    int r  = lane & 15;       // fragment row within 16
    int s0 = lane >> 4;       // 16B k-slot 0..3 (within a 32-k chunk)

    for (int kt = 0; kt < FI / 64; ++kt) {
        // stage 64x64 bf16 tiles: 512 16B-units each, 2 per thread
        #pragma unroll
        for (int t = 0; t < 2; ++t) {
            int q   = t * 256 + tid;
            int row = q >> 3;                     // 8 slots per row
            int sl  = q & 7;
            int sg  = sl ^ (row & 7);             // pre-swizzled source slot
            GLOAD_LDS16(xb  + (size_t)(bm + row) * FI + kt * 64 + sg * 8, As + q * 8);
            GLOAD_LDS16(W1t + (size_t)(bn + row) * FI + kt * 64 + sg * 8, Bs + q * 8);
        }
        __syncthreads();

        #pragma unroll
        for (int kc = 0; kc < 2; ++kc) {          // two k=32 chunks, ascending k order
            short8 a[2], b[2];
            #pragma unroll
            for (int m = 0; m < 2; ++m) {
                int row = wm * 32 + m * 16 + r;
                int sl  = (kc * 4 + s0) ^ (row & 7);
                a[m] = *reinterpret_cast<const short8*>(As + row * 64 + sl * 8);
            }
            #pragma unroll
            for (int n = 0; n < 2; ++n) {
                int row = wn * 32 + n * 16 + r;
                int sl  = (kc * 4 + s0) ^ (row & 7);
                b[n] = *reinterpret_cast<const short8*>(Bs + row * 64 + sl * 8);
            }
            #pragma unroll
            for (int m = 0; m < 2; ++m)
                #pragma unroll
                for (int n = 0; n < 2; ++n)
                    acc[m][n] = __builtin_amdgcn_mfma_f32_16x16x32_bf16(a[m], b[n], acc[m][n], 0, 0, 0);
        }
        __syncthreads();
    }

    // C/D layout: col = lane&15, row = (lane>>4)*4 + reg  [m89-verified]
    #pragma unroll
    for (int m = 0; m < 2; ++m) {
        #pragma unroll
        for (int n = 0; n < 2; ++n) {
            int col = bn + wn * 32 + n * 16 + (lane & 15);
            int rw0 = bm + wm * 32 + m * 16 + (lane >> 4) * 4;
            #pragma unroll
            for (int reg = 0; reg < 4; ++reg) {
                float v = acc[m][n][reg];
                int pk = __builtin_amdgcn_cvt_pk_fp8_f32(v, v, 0, false);
                h8[(size_t)(rw0 + reg) * FH + col] = (unsigned char)(pk & 0xff);
            }
        }
    }
}

// ---- fp8x8 packed accumulate: 4 cvt_pk + 4 pk_fma per row ----
__device__ __forceinline__ void accp(f32x2* __restrict__ acc, uint2 rv, float w) {
    f32x2 wv = {w, w};
    acc[0] += wv * __builtin_amdgcn_cvt_pk_f32_fp8((int)rv.x, false);
    acc[1] += wv * __builtin_amdgcn_cvt_pk_f32_fp8((int)rv.x, true);
    acc[2] += wv * __builtin_amdgcn_cvt_pk_f32_fp8((int)rv.y, false);
    acc[3] += wv * __builtin_amdgcn_cvt_pk_f32_fp8((int)rv.y, true);
}

// ------- fused: agg1[v] = relu(sum w*h8[src] + b1); z[v] = dot(agg1[v], W2) -------
// one wave per node; lane owns feats [lane*8, lane*8+8); fp8 row = 512B, L2-resident
__global__ __launch_bounds__(256) void k_agg(const unsigned char* __restrict__ h8,
                                             const int* __restrict__ row_ptr,
                                             const int2* __restrict__ csr,
                                             const float* __restrict__ b1,
                                             const float* __restrict__ W2,
                                             float* __restrict__ z) {
    int lane = threadIdx.x & 63;
    int v = blockIdx.x * 4 + (threadIdx.x >> 6);
    f32x2 acc[4] = {};
    int p0 = row_ptr[v], p1 = row_ptr[v + 1];
    for (int base = p0; base < p1; base += 64) {
        int cnt = p1 - base; if (cnt > 64) cnt = 64;
        int2 sw = (lane < cnt) ? csr[base + lane] : make_int2(0, 0);
        int j = 0;
        for (; j + 4 <= cnt; j += 4) {
            int   s0 = __shfl(sw.x, j),     s1 = __shfl(sw.x, j + 1);
            int   s2 = __shfl(sw.x, j + 2), s3 = __shfl(sw.x, j + 3);
            float w0 = __int_as_float(__shfl(sw.y, j));
            float w1 = __int_as_float(__shfl(sw.y, j + 1));
            float w2 = __int_as_float(__shfl(sw.y, j + 2));
            float w3 = __int_as_float(__shfl(sw.y, j + 3));
            uint2 r0 = *reinterpret_cast<const uint2*>(h8 + (size_t)s0 * FH + lane * 8);
            uint2 r1 = *reinterpret_cast<const uint2*>(h8 + (size_t)s1 * FH + lane * 8);
            uint2 r2 = *reinterpret_cast<const uint2*>(h8 + (size_t)s2 * FH + lane * 8);
            uint2 r3 = *reinterpret_cast<const uint2*>(h8 + (size_t)s3 * FH + lane * 8);
            accp(acc, r0, w0);
            accp(acc, r1, w1);
            accp(acc, r2, w2);
            accp(acc, r3, w3);
        }
        for (; j < cnt; ++j) {
            int   sj = __shfl(sw.x, j);
            float wj = __int_as_float(__shfl(sw.y, j));
            uint2 rj = *reinterpret_cast<const uint2*>(h8 + (size_t)sj * FH + lane * 8);
            accp(acc, rj, wj);
        }
    }
    const f32x2* b2p = reinterpret_cast<const f32x2*>(b1 + lane * 8);
    const f32x2* w2p = reinterpret_cast<const f32x2*>(W2 + lane * 8);
    float val = 0.f;
    #pragma unroll
    for (int q = 0; q < 4; ++q) {
        f32x2 t = acc[q] + b2p[q];
        t.x = fmaxf(t.x, 0.f);
        t.y = fmaxf(t.y, 0.f);
        f32x2 r = t * w2p[q];
        val += r.x + r.y;
    }
    #pragma unroll
    for (int off = 32; off; off >>= 1) val += __shfl_down(val, off);
    if (lane == 0) z[v] = val;
}

// ---------------- aggregation 2 (scalar) + ohe ----------------
__global__ void k_node(const float* __restrict__ z,
                       const int* __restrict__ row_ptr,
                       const int2* __restrict__ csr,
                       const float* __restrict__ b2,
                       const float* __restrict__ o,
                       const float* __restrict__ Wl,
                       const float* __restrict__ bl,
                       float* __restrict__ h2, float* __restrict__ ohe) {
    int v = blockIdx.x * blockDim.x + threadIdx.x;
    if (v >= NN) return;
    float acc = 0.f;
    int p1 = row_ptr[v + 1];
    for (int p = row_ptr[v]; p < p1; ++p) {
        int2 sw = csr[p];
        acc += __int_as_float(sw.y) * z[sw.x];
    }
    h2[v] = acc + b2[0];
    float4 ov = *reinterpret_cast<const float4*>(&o[(size_t)v * 4]);
    ohe[v] = ov.x * Wl[0] + ov.y * Wl[1] + ov.z * Wl[2] + ov.w * Wl[3] + bl[0];
}

// -------- out[i][j] = h2[j] + ohe[i]; 2048 blocks, 4 rows/block, h2 row in regs ----
__global__ __launch_bounds__(256) void k_out(const float* __restrict__ h2,
                                             const float* __restrict__ ohe,
                                             float4* __restrict__ out) {
    int i0 = blockIdx.x * 4;
    int t  = threadIdx.x;
    float4 h[8];
    #pragma unroll
    for (int u = 0; u < 8; ++u) h[u] = reinterpret_cast<const float4*>(h2)[u * 256 + t];
    #pragma unroll
    for (int rr = 0; rr < 4; ++rr) {
        float oi = ohe[i0 + rr];
        float4* dst = out + (size_t)(i0 + rr) * 2048;
        #pragma unroll
        for (int u = 0; u < 8; ++u) {
            float4 v = h[u];
            dst[u * 256 + t] = make_float4(v.x + oi, v.y + oi, v.z + oi, v.w + oi);
        }
    }
}

extern "C" void kernel_launch(void* const* d_in, const int* in_sizes, int n_in,
                              void* d_out, int out_size, void* d_ws, size_t ws_size,
                              hipStream_t stream) {
    const float* x  = (const float*)d_in[0];
    const float* o  = (const float*)d_in[1];
    const int*   ei = (const int*)d_in[2];
    const float* W1 = (const float*)d_in[3];
    const float* b1 = (const float*)d_in[4];
    const float* W2 = (const float*)d_in[5];
    const float* b2 = (const float*)d_in[6];
    const float* Wl = (const float*)d_in[7];
    const float* bl = (const float*)d_in[8];
    float* out = (float*)d_out;

    const int E = in_sizes[2] / 2;
    const int* src = ei;
    const int* dst = ei + E;

    // workspace carve-up (256B aligned)
    char* p = (char*)d_ws;
    auto alloc = [&](size_t bytes) {
        char* r = p;
        p += (bytes + 255) & ~(size_t)255;
        return r;
    };
    int*   deg     = (int*)  alloc(NN * 4);
    float* dinv    = (float*)alloc(NN * 4);
    int*   row_ptr = (int*)  alloc((NN + 1) * 4);
    int*   cursor  = (int*)  alloc(NN * 4);
    int2*  csr     = (int2*) alloc((size_t)(E + NN) * 8);
    unsigned short* xb  = (unsigned short*)alloc((size_t)NN * FI * 2);
    unsigned short* W1t = (unsigned short*)alloc((size_t)FH * FI * 2);
    unsigned char*  h8  = (unsigned char*) alloc((size_t)NN * FH);
    float* z       = (float*)alloc(NN * 4);
    float* h2      = (float*)alloc(NN * 4);
    float* ohe     = (float*)alloc(NN * 4);

    k_prep <<<1120, 256, 0, stream>>>(x, W1, xb, W1t, deg, cursor);
    k_deg  <<<(E + 255) / 256, 256, 0, stream>>>(dst, E, deg);
    k_scan <<<1, 1024, 0, stream>>>(deg, row_ptr, dinv);
    k_fill <<<(E + NN + 255) / 256, 256, 0, stream>>>(src, dst, E, dinv, row_ptr, cursor, csr);
    k_gemm <<<dim3(FH / 64, NN / 64), 256, 0, stream>>>(xb, W1t, h8);
    k_agg  <<<NN / 4, 256, 0, stream>>>(h8, row_ptr, csr, b1, W2, z);
    k_node <<<(NN + 255) / 256, 256, 0, stream>>>(z, row_ptr, csr, b2, o, Wl, bl, h2, ohe);
    k_out  <<<NN / 4, 256, 0, stream>>>(h2, ohe, (float4*)out);
}

// Round 13
// 132.934 us; speedup vs baseline: 1.1555x; 1.0599x over previous
//
#include <hip/hip_runtime.h>

#define NN 8192      // nodes
#define FI 512       // in features
#define FH 512       // hidden features

typedef __attribute__((ext_vector_type(8))) short short8;
typedef __attribute__((ext_vector_type(4))) float f32x4;
typedef __attribute__((ext_vector_type(2))) float f32x2;

__device__ __forceinline__ unsigned short f2bf(float f) {
    unsigned u = __float_as_uint(f);
    unsigned r = (u + 0x7fff + ((u >> 16) & 1)) >> 16;   // RNE
    return (unsigned short)r;
}

#define GLOAD_LDS16(g, l)                                                        \
    __builtin_amdgcn_global_load_lds((__attribute__((address_space(1))) const void*)(g), \
                                     (__attribute__((address_space(3))) void*)(l), 16, 0, 0)

// =============== D1: zero deg + cursor (contiguous 16384 ints) ==================
__global__ void k_zero(int* __restrict__ zero_base) {
    zero_base[blockIdx.x * 256 + threadIdx.x] = 0;
}

// =============== D2: prep (x->bf16, W1^T->bf16) ∥ degree count ==================
//  blocks 0..1023    : cvt x -> bf16 (4 float4/thread)
//  blocks 1024..1087 : W1 transpose -> bf16 via padded LDS tile
//  blocks 1088..2111 : degree count over E edges
__global__ __launch_bounds__(256) void k_prepdeg(const float* __restrict__ x,
                                                 const float* __restrict__ W1,
                                                 const int* __restrict__ dstE, int E,
                                                 unsigned short* __restrict__ xb,
                                                 unsigned short* __restrict__ W1t,
                                                 int* __restrict__ deg) {
    int b = blockIdx.x, t = threadIdx.x;
    if (b < 1024) {
        #pragma unroll
        for (int u = 0; u < 4; ++u) {
            int i = (b * 4 + u) * 256 + t;           // 1M float4 units total
            float4 v = reinterpret_cast<const float4*>(x)[i];
            ushort4 h;
            h.x = f2bf(v.x); h.y = f2bf(v.y); h.z = f2bf(v.z); h.w = f2bf(v.w);
            reinterpret_cast<ushort4*>(xb)[i] = h;
        }
    } else if (b < 1088) {
        __shared__ float tile[64][65];
        int bi = (b - 1024) >> 3;                    // k-tile
        int bj = (b - 1024) & 7;                     // n-tile
        int c = t & 63, r0 = t >> 6;
        #pragma unroll
        for (int rr = 0; rr < 16; ++rr) {
            int row = rr * 4 + r0;
            tile[row][c] = W1[(size_t)(bi * 64 + row) * FH + bj * 64 + c];
        }
        __syncthreads();
        #pragma unroll
        for (int rr = 0; rr < 16; ++rr) {
            int row = rr * 4 + r0;                   // n within tile
            W1t[(size_t)(bj * 64 + row) * FI + bi * 64 + c] = f2bf(tile[c][row]);
        }
    } else {
        int i = (b - 1088) * 256 + t;
        if (i < E) atomicAdd(&deg[dstE[i]], 1);
    }
}

// =============== D3: prefix scan over row lengths (deg+1) + dinv ================
__global__ __launch_bounds__(1024) void k_scan(const int* __restrict__ deg,
                                               int* __restrict__ row_ptr,
                                               float* __restrict__ dinv) {
    __shared__ int lds[1024];
    int tid = threadIdx.x;
    int base = tid * 8;
    int l[8]; int s = 0;
    #pragma unroll
    for (int u = 0; u < 8; ++u) {
        l[u] = deg[base + u] + 1;                       // +1 self loop
        dinv[base + u] = rsqrtf((float)l[u]);
        s += l[u];
    }
    lds[tid] = s;
    __syncthreads();
    for (int off = 1; off < 1024; off <<= 1) {
        int add = (tid >= off) ? lds[tid - off] : 0;
        __syncthreads();
        lds[tid] += add;
        __syncthreads();
    }
    int run = lds[tid] - s;  // exclusive prefix
    #pragma unroll
    for (int u = 0; u < 8; ++u) { row_ptr[base + u] = run; run += l[u]; }
    if (tid == 1023) row_ptr[NN] = lds[1023];
}

// =============== D4: CSR fill (blocks 0..1055) ∥ GEMM (1056..2079) ==============
__global__ __launch_bounds__(256) void k_fillgemm(const int* __restrict__ srcE,
                                                  const int* __restrict__ dstE, int E,
                                                  const float* __restrict__ dinv,
                                                  const int* __restrict__ row_ptr,
                                                  int* __restrict__ cursor,
                                                  int2* __restrict__ csr,
                                                  const unsigned short* __restrict__ xb,
                                                  const unsigned short* __restrict__ W1t,
                                                  unsigned char* __restrict__ h8) {
    __shared__ __align__(16) unsigned short As[64 * 64];
    __shared__ __align__(16) unsigned short Bs[64 * 64];
    int bid = blockIdx.x, tid = threadIdx.x;

    if (bid < 1056) {                 // ---- CSR fill ----
        int i = bid * 256 + tid;
        if (i < E) {
            int s = srcE[i], d = dstE[i];
            int p = row_ptr[d] + atomicAdd(&cursor[d], 1);
            csr[p] = make_int2(s, __float_as_int(dinv[s] * dinv[d]));
        } else if (i < E + NN) {
            int v = i - E;
            int p = row_ptr[v] + atomicAdd(&cursor[v], 1);
            csr[p] = make_int2(v, __float_as_int(dinv[v] * dinv[v]));
        }
        return;
    }

    // ---- bf16 MFMA GEMM, BM=BN=BK=64; epilogue -> fp8 e4m3 ----
    int q0 = bid - 1056;
    int lane = tid & 63;
    int wave = tid >> 6;
    int wm = wave >> 1, wn = wave & 1;           // 2x2 wave grid, 32x32 per wave
    int bm = (q0 >> 3) * 64, bn = (q0 & 7) * 64;

    f32x4 acc[2][2] = {};
    int r  = lane & 15;       // fragment row within 16
    int s0 = lane >> 4;       // 16B k-slot 0..3 (within a 32-k chunk)

    for (int kt = 0; kt < FI / 64; ++kt) {
        #pragma unroll
        for (int t = 0; t < 2; ++t) {
            int q   = t * 256 + tid;
            int row = q >> 3;                     // 8 slots per row
            int sl  = q & 7;
            int sg  = sl ^ (row & 7);             // pre-swizzled source slot
            GLOAD_LDS16(xb  + (size_t)(bm + row) * FI + kt * 64 + sg * 8, As + q * 8);
            GLOAD_LDS16(W1t + (size_t)(bn + row) * FI + kt * 64 + sg * 8, Bs + q * 8);
        }
        __syncthreads();

        #pragma unroll
        for (int kc = 0; kc < 2; ++kc) {          // two k=32 chunks, ascending k order
            short8 a[2], b[2];
            #pragma unroll
            for (int m = 0; m < 2; ++m) {
                int row = wm * 32 + m * 16 + r;
                int sl  = (kc * 4 + s0) ^ (row & 7);
                a[m] = *reinterpret_cast<const short8*>(As + row * 64 + sl * 8);
            }
            #pragma unroll
            for (int n = 0; n < 2; ++n) {
                int row = wn * 32 + n * 16 + r;
                int sl  = (kc * 4 + s0) ^ (row & 7);
                b[n] = *reinterpret_cast<const short8*>(Bs + row * 64 + sl * 8);
            }
            #pragma unroll
            for (int m = 0; m < 2; ++m)
                #pragma unroll
                for (int n = 0; n < 2; ++n)
                    acc[m][n] = __builtin_amdgcn_mfma_f32_16x16x32_bf16(a[m], b[n], acc[m][n], 0, 0, 0);
        }
        __syncthreads();
    }

    // C/D layout: col = lane&15, row = (lane>>4)*4 + reg  [m89-verified]
    #pragma unroll
    for (int m = 0; m < 2; ++m) {
        #pragma unroll
        for (int n = 0; n < 2; ++n) {
            int col = bn + wn * 32 + n * 16 + (lane & 15);
            int rw0 = bm + wm * 32 + m * 16 + (lane >> 4) * 4;
            #pragma unroll
            for (int reg = 0; reg < 4; ++reg) {
                float v = acc[m][n][reg];
                int pk = __builtin_amdgcn_cvt_pk_fp8_f32(v, v, 0, false);
                h8[(size_t)(rw0 + reg) * FH + col] = (unsigned char)(pk & 0xff);
            }
        }
    }
}

// ---- fp8x8 packed accumulate: 4 cvt_pk + 4 pk_fma per row ----
__device__ __forceinline__ void accp(f32x2* __restrict__ acc, uint2 rv, float w) {
    f32x2 wv = {w, w};
    acc[0] += wv * __builtin_amdgcn_cvt_pk_f32_fp8((int)rv.x, false);
    acc[1] += wv * __builtin_amdgcn_cvt_pk_f32_fp8((int)rv.x, true);
    acc[2] += wv * __builtin_amdgcn_cvt_pk_f32_fp8((int)rv.y, false);
    acc[3] += wv * __builtin_amdgcn_cvt_pk_f32_fp8((int)rv.y, true);
}

// ------- D5: agg1[v] = relu(sum w*h8[src] + b1); z[v] = dot(agg1[v], W2) -------
__global__ __launch_bounds__(256) void k_agg(const unsigned char* __restrict__ h8,
                                             const int* __restrict__ row_ptr,
                                             const int2* __restrict__ csr,
                                             const float* __restrict__ b1,
                                             const float* __restrict__ W2,
                                             float* __restrict__ z) {
    int lane = threadIdx.x & 63;
    int v = blockIdx.x * 4 + (threadIdx.x >> 6);
    f32x2 acc[4] = {};
    int p0 = row_ptr[v], p1 = row_ptr[v + 1];
    for (int base = p0; base < p1; base += 64) {
        int cnt = p1 - base; if (cnt > 64) cnt = 64;
        int2 sw = (lane < cnt) ? csr[base + lane] : make_int2(0, 0);
        int j = 0;
        for (; j + 4 <= cnt; j += 4) {
            int   s0 = __shfl(sw.x, j),     s1 = __shfl(sw.x, j + 1);
            int   s2 = __shfl(sw.x, j + 2), s3 = __shfl(sw.x, j + 3);
            float w0 = __int_as_float(__shfl(sw.y, j));
            float w1 = __int_as_float(__shfl(sw.y, j + 1));
            float w2 = __int_as_float(__shfl(sw.y, j + 2));
            float w3 = __int_as_float(__shfl(sw.y, j + 3));
            uint2 r0 = *reinterpret_cast<const uint2*>(h8 + (size_t)s0 * FH + lane * 8);
            uint2 r1 = *reinterpret_cast<const uint2*>(h8 + (size_t)s1 * FH + lane * 8);
            uint2 r2 = *reinterpret_cast<const uint2*>(h8 + (size_t)s2 * FH + lane * 8);
            uint2 r3 = *reinterpret_cast<const uint2*>(h8 + (size_t)s3 * FH + lane * 8);
            accp(acc, r0, w0);
            accp(acc, r1, w1);
            accp(acc, r2, w2);
            accp(acc, r3, w3);
        }
        for (; j < cnt; ++j) {
            int   sj = __shfl(sw.x, j);
            float wj = __int_as_float(__shfl(sw.y, j));
            uint2 rj = *reinterpret_cast<const uint2*>(h8 + (size_t)sj * FH + lane * 8);
            accp(acc, rj, wj);
        }
    }
    const f32x2* b2p = reinterpret_cast<const f32x2*>(b1 + lane * 8);
    const f32x2* w2p = reinterpret_cast<const f32x2*>(W2 + lane * 8);
    float val = 0.f;
    #pragma unroll
    for (int q = 0; q < 4; ++q) {
        f32x2 t = acc[q] + b2p[q];
        t.x = fmaxf(t.x, 0.f);
        t.y = fmaxf(t.y, 0.f);
        f32x2 r = t * w2p[q];
        val += r.x + r.y;
    }
    #pragma unroll
    for (int off = 32; off; off >>= 1) val += __shfl_down(val, off);
    if (lane == 0) z[v] = val;
}

// ---------------- D6: aggregation 2 (scalar) + ohe ----------------
__global__ void k_node(const float* __restrict__ z,
                       const int* __restrict__ row_ptr,
                       const int2* __restrict__ csr,
                       const float* __restrict__ b2,
                       const float* __restrict__ o,
                       const float* __restrict__ Wl,
                       const float* __restrict__ bl,
                       float* __restrict__ h2, float* __restrict__ ohe) {
    int v = blockIdx.x * blockDim.x + threadIdx.x;
    if (v >= NN) return;
    float acc = 0.f;
    int p1 = row_ptr[v + 1];
    for (int p = row_ptr[v]; p < p1; ++p) {
        int2 sw = csr[p];
        acc += __int_as_float(sw.y) * z[sw.x];
    }
    h2[v] = acc + b2[0];
    float4 ov = *reinterpret_cast<const float4*>(&o[(size_t)v * 4]);
    ohe[v] = ov.x * Wl[0] + ov.y * Wl[1] + ov.z * Wl[2] + ov.w * Wl[3] + bl[0];
}

// -------- D7: out[i][j] = h2[j] + ohe[i]; 2048 blocks, h2 row in regs ----
__global__ __launch_bounds__(256) void k_out(const float* __restrict__ h2,
                                             const float* __restrict__ ohe,
                                             float4* __restrict__ out) {
    int i0 = blockIdx.x * 4;
    int t  = threadIdx.x;
    float4 h[8];
    #pragma unroll
    for (int u = 0; u < 8; ++u) h[u] = reinterpret_cast<const float4*>(h2)[u * 256 + t];
    #pragma unroll
    for (int rr = 0; rr < 4; ++rr) {
        float oi = ohe[i0 + rr];
        float4* dst = out + (size_t)(i0 + rr) * 2048;
        #pragma unroll
        for (int u = 0; u < 8; ++u) {
            float4 v = h[u];
            dst[u * 256 + t] = make_float4(v.x + oi, v.y + oi, v.z + oi, v.w + oi);
        }
    }
}

extern "C" void kernel_launch(void* const* d_in, const int* in_sizes, int n_in,
                              void* d_out, int out_size, void* d_ws, size_t ws_size,
                              hipStream_t stream) {
    const float* x  = (const float*)d_in[0];
    const float* o  = (const float*)d_in[1];
    const int*   ei = (const int*)d_in[2];
    const float* W1 = (const float*)d_in[3];
    const float* b1 = (const float*)d_in[4];
    const float* W2 = (const float*)d_in[5];
    const float* b2 = (const float*)d_in[6];
    const float* Wl = (const float*)d_in[7];
    const float* bl = (const float*)d_in[8];
    float* out = (float*)d_out;

    const int E = in_sizes[2] / 2;
    const int* src = ei;
    const int* dst = ei + E;

    // workspace carve-up (256B aligned); deg+cursor contiguous for k_zero
    char* p = (char*)d_ws;
    auto alloc = [&](size_t bytes) {
        char* r = p;
        p += (bytes + 255) & ~(size_t)255;
        return r;
    };
    int*   deg     = (int*)  alloc(NN * 4);   // 32 KB
    int*   cursor  = (int*)  alloc(NN * 4);   // 32 KB (directly follows deg)
    float* dinv    = (float*)alloc(NN * 4);
    int*   row_ptr = (int*)  alloc((NN + 1) * 4);
    int2*  csr     = (int2*) alloc((size_t)(E + NN) * 8);
    unsigned short* xb  = (unsigned short*)alloc((size_t)NN * FI * 2);
    unsigned short* W1t = (unsigned short*)alloc((size_t)FH * FI * 2);
    unsigned char*  h8  = (unsigned char*) alloc((size_t)NN * FH);
    float* z       = (float*)alloc(NN * 4);
    float* h2      = (float*)alloc(NN * 4);
    float* ohe     = (float*)alloc(NN * 4);

    k_zero    <<<64, 256, 0, stream>>>(deg);   // deg + cursor (contiguous 16384 ints)
    k_prepdeg <<<1088 + (E + 255) / 256, 256, 0, stream>>>(x, W1, dst, E, xb, W1t, deg);
    k_scan    <<<1, 1024, 0, stream>>>(deg, row_ptr, dinv);
    k_fillgemm<<<1056 + 1024, 256, 0, stream>>>(src, dst, E, dinv, row_ptr, cursor, csr,
                                                xb, W1t, h8);
    k_agg     <<<NN / 4, 256, 0, stream>>>(h8, row_ptr, csr, b1, W2, z);
    k_node    <<<(NN + 255) / 256, 256, 0, stream>>>(z, row_ptr, csr, b2, o, Wl, bl, h2, ohe);
    k_out     <<<NN / 4, 256, 0, stream>>>(h2, ohe, (float4*)out);
}